// Round 6
// baseline (37.625 us; speedup 1.0000x reference)
//
#include <hip/hip_runtime.h>
#include <hip/hip_bf16.h>
#include <string.h>

// TaylorLayer via MFMA: out[B,8] = relu(W[8,164] @ epd[164,B] + b), B=262144.
//
// R6: MEASUREMENT ROUND. Kernel identical to R5. taylor_mfma is launched
// 4x (idempotent: every launch writes the same values). True kernel time
// k = (dur_R6 - dur_R5)/3, independent of any fixed graph/launch overhead.
// Five structurally different kernels (R1-R5) all landed 17-21us vs ~3-5us
// issue-rate models -> suspect fixed ~14us harness overhead (rocprof.md:
// "launch overhead (~10us) can dominate").

static constexpr int TEXP = 164;
static constexpr int NOUT = 8;
static constexpr int NMFMA = 11;   // K = 176
static constexpr int HALF = 88;    // monomial slots per k-half

using f32x16 = __attribute__((ext_vector_type(16))) float;
using short8 = __attribute__((ext_vector_type(8))) short;

constexpr int rowstart2(int j) { return j * 8 - j * (j - 1) / 2; }
constexpr int start3(int j) {
  int s = 44;
  for (int jp = 0; jp < j; ++jp) s += (8 - jp) * (9 - jp) / 2;
  return s;
}
struct D3 { int j, p; };
constexpr D3 d3idx(int M) {
  int j = 0;
  while (start3(j + 1) <= M) ++j;
  int q = M - start3(j);
  int a = j;
  while (q >= (8 - a)) { q -= (8 - a); ++a; }
  int b = a + q;
  return { j, rowstart2(a) + (b - a) };
}

template <int M>
__device__ __forceinline__ float mono(const float (&xv)[8], const float (&d2)[36]) {
  if constexpr (M < 8) {
    return xv[M];
  } else if constexpr (M < 44) {
    return d2[M - 8];
  } else {
    constexpr D3 t = d3idx(M);
    return xv[t.j] * d2[t.p];
  }
}

__device__ __forceinline__ short bf16bits(float v) {
  __hip_bfloat16 h = __float2bfloat16(v);
  short s;
  memcpy(&s, &h, 2);
  return s;
}

template <int C>
__device__ __forceinline__ void do_slot(const float (&xv)[8], const float (&d2)[36],
                                        bool hi, short8& bv) {
  float v0 = mono<C>(xv, d2);
  float v1;
  if constexpr (HALF + C < TEXP) v1 = mono<HALF + C>(xv, d2);
  else v1 = 0.0f;
  float v = hi ? v1 : v0;
  bv[C & 7] = bf16bits(v);
}

template <int I>
__device__ __forceinline__ void slot8(const float (&xv)[8], const float (&d2)[36],
                                      bool hi, short8& bv) {
  do_slot<8 * I + 0>(xv, d2, hi, bv);
  do_slot<8 * I + 1>(xv, d2, hi, bv);
  do_slot<8 * I + 2>(xv, d2, hi, bv);
  do_slot<8 * I + 3>(xv, d2, hi, bv);
  do_slot<8 * I + 4>(xv, d2, hi, bv);
  do_slot<8 * I + 5>(xv, d2, hi, bv);
  do_slot<8 * I + 6>(xv, d2, hi, bv);
  do_slot<8 * I + 7>(xv, d2, hi, bv);
}

template <int I>
struct MfmaStep {
  static __device__ __forceinline__ void run(const float (&xv)[8], const float (&d2)[36],
                                             bool hi, const unsigned short* __restrict__ wpl,
                                             short8 af_cur, f32x16& acc) {
    short8 af_next;
    if constexpr (I + 1 < NMFMA)
      af_next = *reinterpret_cast<const short8*>(wpl + (I + 1) * 64 * 8);
    short8 bv;
    slot8<I>(xv, d2, hi, bv);
    acc = __builtin_amdgcn_mfma_f32_32x32x16_bf16(af_cur, bv, acc, 0, 0, 0);
    __builtin_amdgcn_sched_barrier(0);
    if constexpr (I + 1 < NMFMA)
      MfmaStep<I + 1>::run(xv, d2, hi, wpl, af_next, acc);
  }
};

__global__ void prep_w(const float* __restrict__ W, unsigned short* __restrict__ wp) {
  for (int idx = threadIdx.x + blockIdx.x * blockDim.x; idx < NMFMA * 64 * 8;
       idx += blockDim.x * gridDim.x) {
    int j = idx & 7;
    int lane = (idx >> 3) & 63;
    int i = idx >> 9;
    int row = lane & 31, h = lane >> 5;
    int m = HALF * h + 8 * i + j;
    float v = (row < NOUT && m < TEXP) ? W[row * TEXP + m] : 0.0f;
    union { float f; unsigned int u; } c; c.f = v;
    unsigned int u = c.u;
    wp[idx] = (unsigned short)((u + 0x7fffu + ((u >> 16) & 1u)) >> 16);  // RNE
  }
}

__global__ __launch_bounds__(256, 4) void taylor_mfma(
    const float* __restrict__ x, const float* __restrict__ b,
    const unsigned short* __restrict__ wp, float* __restrict__ out, int ngroups) {
  const int lane = (int)(threadIdx.x & 63);
  const bool hi = lane >= 32;
  const int h = hi ? 1 : 0;
  const int col = lane & 31;

  const unsigned short* wpl = wp + lane * 8;
  short8 af0 = *reinterpret_cast<const short8*>(wpl);

  const float4 bv4 = *reinterpret_cast<const float4*>(b + 4 * h);

  const int g = (int)((blockIdx.x * blockDim.x + threadIdx.x) >> 6);
  if (g >= ngroups) return;

  const int elem = g * 32 + col;
  float4 xa = reinterpret_cast<const float4*>(x)[elem * 2 + 0];
  float4 xb = reinterpret_cast<const float4*>(x)[elem * 2 + 1];
  float xv[8] = {xa.x, xa.y, xa.z, xa.w, xb.x, xb.y, xb.z, xb.w};

  float d2[36];
#pragma unroll
  for (int j = 0; j < 8; ++j) {
#pragma unroll
    for (int k = j; k < 8; ++k) {
      d2[rowstart2(j) + (k - j)] = xv[j] * xv[k];
    }
  }

  f32x16 acc;
#pragma unroll
  for (int r = 0; r < 16; ++r) acc[r] = 0.0f;

  MfmaStep<0>::run(xv, d2, hi, wpl, af0, acc);

  float4 o;
  o.x = fmaxf(acc[0] + bv4.x, 0.0f);
  o.y = fmaxf(acc[1] + bv4.y, 0.0f);
  o.z = fmaxf(acc[2] + bv4.z, 0.0f);
  o.w = fmaxf(acc[3] + bv4.w, 0.0f);
  *reinterpret_cast<float4*>(out + elem * 8 + 4 * h) = o;
}

extern "C" void kernel_launch(void* const* d_in, const int* in_sizes, int n_in,
                              void* d_out, int out_size, void* d_ws, size_t ws_size,
                              hipStream_t stream) {
  const float* x = (const float*)d_in[0];   // [262144, 8, 1]
  const float* W = (const float*)d_in[1];   // [8, 164]
  const float* b = (const float*)d_in[2];   // [8, 1]
  float* out = (float*)d_out;               // [262144, 8]
  unsigned short* wp = (unsigned short*)d_ws;  // 11*64*8 bf16 = 11264 B

  int n = in_sizes[0] / 8;      // 262144 elements
  int ngroups = n / 32;         // 8192 wave-groups
  int blocks = ngroups / 4;     // 2048 blocks

  prep_w<<<8, 256, 0, stream>>>(W, wp);
  // 4x identical launches (idempotent) -> k = (dur_R6 - dur_R5)/3
  taylor_mfma<<<blocks, 256, 0, stream>>>(x, b, wp, out, ngroups);
  taylor_mfma<<<blocks, 256, 0, stream>>>(x, b, wp, out, ngroups);
  taylor_mfma<<<blocks, 256, 0, stream>>>(x, b, wp, out, ngroups);
  taylor_mfma<<<blocks, 256, 0, stream>>>(x, b, wp, out, ngroups);
}

// Round 7
// 16.258 us; speedup vs baseline: 2.3143x; 2.3143x over previous
//
#include <hip/hip_runtime.h>
#include <hip/hip_bf16.h>
#include <string.h>

// TaylorLayer via MFMA: out[B,8] = relu(W[8,164] @ epd[164,B] + b), B=262144.
// epd = monomials deg 1..3 of x[8], reference recursion order, T=164.
//
// R6 measurement: true kernel ~6.8us, fixed harness overhead ~10.5us.
// R7: sigma-symmetry restructure. Involution s(j)=j^4 on variables maps the
// monomial set to itself (4 fixed: x_j*x_{j+4}; 80 2-orbits). Half-0 lanes
// get orbit reps (>=2 low indices); half-1 lanes compute THE SAME slot
// program on permuted inputs xs = sigma(xv) (8 cndmask once), since
// sigma(m)(x) = m(sigma(x)). Eliminates the per-slot dual-compute + 88
// cndmask of R3-R6 (156 muls+88 sel -> 94 muls+8 sel). W permuted to match
// via constexpr tables; duplicated fixed monomials: W in half0, 0 in half1.
//
// MFMA mfma_f32_32x32x16_bf16, K=176 (4 zero-pad slots + 4 dup slots).
// A: row=lane&31 (rows 8..31 zero), half h=lane>>5, slot 8i+j (prep_w).
// B: col=lane&31, same k-map (A/B symmetric). C/D: col=lane&31,
// row=(reg&3)+8*(reg>>2)+4*(lane>>5) -> regs 0..3 = rows 4h+0..3.

static constexpr int TEXP = 164;
static constexpr int NOUT = 8;
static constexpr int NMFMA = 11;   // K = 176
static constexpr int NSLOT = 88;   // slots per k-half

using f32x16 = __attribute__((ext_vector_type(16))) float;
using short8 = __attribute__((ext_vector_type(8))) short;

// ---- reference t-order index math ----
constexpr int rowstart2(int j) { return j * 8 - j * (j - 1) / 2; }
constexpr int start3(int j) {
  int s = 44;
  for (int jp = 0; jp < j; ++jp) s += (8 - jp) * (9 - jp) / 2;
  return s;
}
constexpr int t3_of(int a, int b, int c) {  // sorts, then reference offset
  int x = a, y = b, z = c, t = 0;
  if (x > y) { t = x; x = y; y = t; }
  if (y > z) { t = y; y = z; z = t; }
  if (x > y) { t = x; x = y; y = t; }
  int off = 0;
  for (int ap = x; ap < y; ++ap) off += 8 - ap;
  return start3(x) + off + (z - y);
}

// ---- slot table: 88 half-0 representatives ----
struct Slot { int deg, a, b, c; };
struct SlotTable { Slot s[NSLOT]; };

constexpr bool isrep2(int j, int k) {      // j<=k
  if (k < 4) return true;                  // low-low
  if (j >= 4) return false;                // high-high = sigma(low-low)
  if (k == j + 4) return true;             // fixed (dup; W zero in half1)
  return j < k - 4;                        // mixed: rep iff j < sigma-partner's j
}
constexpr bool isrep3(int a, int b, int c) {
  return ((a < 4) + (b < 4) + (c < 4)) >= 2;  // sorted => a,b are the lows
}

constexpr SlotTable make_slots() {
  SlotTable T{};
  int s = 0;
  for (int j = 0; j < 4; ++j) T.s[s++] = {1, j, 0, 0};                 // 4
  for (int j = 0; j < 8; ++j)
    for (int k = j; k < 8; ++k)
      if (isrep2(j, k)) T.s[s++] = {2, j, k, 0};                       // 20
  for (int a = 0; a < 8; ++a)
    for (int b = a; b < 8; ++b)
      for (int c = b; c < 8; ++c)
        if (isrep3(a, b, c)) T.s[s++] = {3, a, b, c};                  // 60
  for (; s < NSLOT; ++s) T.s[s] = {0, 0, 0, 0};                        // 4 pads
  return T;
}
constexpr SlotTable SLOTS = make_slots();

// ---- per-(half,slot) -> reference t index (or -1 => W = 0) ----
struct TT { short t[2][NSLOT]; };
constexpr TT make_tt() {
  TT r{};
  for (int h = 0; h < 2; ++h)
    for (int s = 0; s < NSLOT; ++s) {
      Slot sl = SLOTS.s[s];
      int m = h ? 4 : 0;
      if (sl.deg == 0) { r.t[h][s] = -1; }
      else if (sl.deg == 1) { r.t[h][s] = (short)(sl.a ^ m); }
      else if (sl.deg == 2) {
        if (h == 1 && sl.b == (sl.a ^ 4)) { r.t[h][s] = -1; }  // dup-fixed
        else {
          int a = sl.a ^ m, b = sl.b ^ m;
          int lo = a < b ? a : b, hi2 = a < b ? b : a;
          r.t[h][s] = (short)(8 + rowstart2(lo) + (hi2 - lo));
        }
      } else {
        r.t[h][s] = (short)t3_of(sl.a ^ m, sl.b ^ m, sl.c ^ m);
      }
    }
  return r;
}
__device__ const TT TDX = make_tt();

__device__ __forceinline__ short bf16bits(float v) {
  __hip_bfloat16 h = __float2bfloat16(v);
  short s;
  memcpy(&s, &h, 2);
  return s;
}

// slot value from permuted inputs xs and d2 over xs (only j<4 rows filled)
template <int S>
__device__ __forceinline__ float slotval(const float (&xs)[8], const float (&d2)[36]) {
  constexpr int deg = SLOTS.s[S].deg;
  constexpr int a = SLOTS.s[S].a;
  constexpr int b = SLOTS.s[S].b;
  constexpr int c = SLOTS.s[S].c;
  if constexpr (deg == 1) return xs[a];
  else if constexpr (deg == 2) return d2[rowstart2(a) + (b - a)];       // a < 4
  else if constexpr (deg == 3) return xs[a] * d2[rowstart2(b) + (c - b)]; // b < 4
  else return 0.0f;
}

template <int I>
struct MfmaStep {
  static __device__ __forceinline__ void run(const float (&xs)[8], const float (&d2)[36],
                                             const unsigned short* __restrict__ wpl,
                                             short8 af_cur, f32x16& acc) {
    short8 af_next;
    if constexpr (I + 1 < NMFMA)
      af_next = *reinterpret_cast<const short8*>(wpl + (I + 1) * 64 * 8);
    short8 bv;
    bv[0] = bf16bits(slotval<8 * I + 0>(xs, d2));
    bv[1] = bf16bits(slotval<8 * I + 1>(xs, d2));
    bv[2] = bf16bits(slotval<8 * I + 2>(xs, d2));
    bv[3] = bf16bits(slotval<8 * I + 3>(xs, d2));
    bv[4] = bf16bits(slotval<8 * I + 4>(xs, d2));
    bv[5] = bf16bits(slotval<8 * I + 5>(xs, d2));
    bv[6] = bf16bits(slotval<8 * I + 6>(xs, d2));
    bv[7] = bf16bits(slotval<8 * I + 7>(xs, d2));
    acc = __builtin_amdgcn_mfma_f32_32x32x16_bf16(af_cur, bv, acc, 0, 0, 0);
    __builtin_amdgcn_sched_barrier(0);
    if constexpr (I + 1 < NMFMA)
      MfmaStep<I + 1>::run(xs, d2, wpl, af_next, acc);
  }
};

// ---- prep: wp[(i*64+lane)*8 + j] = bf16(W[row][ TDX[h][8i+j] ]),
// row=lane&31 (0 if >=8), h=lane>>5, -1 => 0 ----
__global__ void prep_w(const float* __restrict__ W, unsigned short* __restrict__ wp) {
  int idx = threadIdx.x + blockIdx.x * blockDim.x;
  if (idx >= NMFMA * 64 * 8) return;
  int j = idx & 7;
  int lane = (idx >> 3) & 63;
  int i = idx >> 9;
  int row = lane & 31, h = lane >> 5;
  int t = TDX.t[h][8 * i + j];
  float v = (row < NOUT && t >= 0) ? W[row * TEXP + t] : 0.0f;
  union { float f; unsigned int u; } c; c.f = v;
  unsigned int u = c.u;
  wp[idx] = (unsigned short)((u + 0x7fffu + ((u >> 16) & 1u)) >> 16);  // RNE
}

__global__ __launch_bounds__(256, 4) void taylor_mfma(
    const float* __restrict__ x, const float* __restrict__ b,
    const unsigned short* __restrict__ wp, float* __restrict__ out, int ngroups) {
  const int lane = (int)(threadIdx.x & 63);
  const bool hi = lane >= 32;
  const int h = hi ? 1 : 0;
  const int col = lane & 31;

  const unsigned short* wpl = wp + lane * 8;
  short8 af0 = *reinterpret_cast<const short8*>(wpl);

  const float4 bv4 = *reinterpret_cast<const float4*>(b + 4 * h);

  const int g = (int)((blockIdx.x * blockDim.x + threadIdx.x) >> 6);
  if (g >= ngroups) return;

  const int elem = g * 32 + col;
  float4 xa = reinterpret_cast<const float4*>(x)[elem * 2 + 0];
  float4 xb = reinterpret_cast<const float4*>(x)[elem * 2 + 1];
  float xv[8] = {xa.x, xa.y, xa.z, xa.w, xb.x, xb.y, xb.z, xb.w};

  // half-1 lanes permute inputs by sigma (j ^ 4): 8 cndmask, then the slot
  // program is identical for both halves.
  float xs[8];
#pragma unroll
  for (int j = 0; j < 8; ++j) xs[j] = hi ? xv[j ^ 4] : xv[j];

  // d2 over xs, only rows j<4 are ever referenced (reps have low pair-lead)
  float d2[36];
#pragma unroll
  for (int j = 0; j < 4; ++j) {
#pragma unroll
    for (int k = j; k < 8; ++k) {
      d2[rowstart2(j) + (k - j)] = xs[j] * xs[k];
    }
  }

  f32x16 acc;
#pragma unroll
  for (int r = 0; r < 16; ++r) acc[r] = 0.0f;

  MfmaStep<0>::run(xs, d2, wpl, af0, acc);

  float4 o;
  o.x = fmaxf(acc[0] + bv4.x, 0.0f);
  o.y = fmaxf(acc[1] + bv4.y, 0.0f);
  o.z = fmaxf(acc[2] + bv4.z, 0.0f);
  o.w = fmaxf(acc[3] + bv4.w, 0.0f);
  *reinterpret_cast<float4*>(out + elem * 8 + 4 * h) = o;
}

extern "C" void kernel_launch(void* const* d_in, const int* in_sizes, int n_in,
                              void* d_out, int out_size, void* d_ws, size_t ws_size,
                              hipStream_t stream) {
  const float* x = (const float*)d_in[0];   // [262144, 8, 1]
  const float* W = (const float*)d_in[1];   // [8, 164]
  const float* b = (const float*)d_in[2];   // [8, 1]
  float* out = (float*)d_out;               // [262144, 8]
  unsigned short* wp = (unsigned short*)d_ws;  // 11*64*8 bf16 = 11264 B

  int n = in_sizes[0] / 8;      // 262144 elements
  int ngroups = n / 32;         // 8192 wave-groups
  int blocks = ngroups / 4;     // 2048 blocks of 4 waves

  prep_w<<<22, 256, 0, stream>>>(W, wp);
  taylor_mfma<<<blocks, 256, 0, stream>>>(x, b, wp, out, ngroups);
}